// Round 1
// baseline (730.887 us; speedup 1.0000x reference)
//
#include <hip/hip_runtime.h>

typedef __bf16 bf16_t;
typedef bf16_t bf16x8 __attribute__((ext_vector_type(8)));
typedef bf16_t bf16x4 __attribute__((ext_vector_type(4)));
typedef float  f32x4  __attribute__((ext_vector_type(4)));

#define T_SEQ 2048
#define C_DIM 1024
#define NH    16
#define DH    64
#define BATCH 4
#define M_TOK (BATCH * T_SEQ)   // 8192

// ---------------------------------------------------------------------------
// prep: x f32 -> bf16 (vectorized float4 -> bf16x4)
// ---------------------------------------------------------------------------
__global__ __launch_bounds__(256) void msa_cvt_x(const float* __restrict__ x,
                                                 bf16_t* __restrict__ xb, int n4) {
  int i = blockIdx.x * 256 + threadIdx.x;
  if (i < n4) {
    const float4 v = ((const float4*)x)[i];
    bf16x4 o;
    o[0] = (bf16_t)v.x; o[1] = (bf16_t)v.y; o[2] = (bf16_t)v.z; o[3] = (bf16_t)v.w;
    ((bf16x4*)xb)[i] = o;
  }
}

// ---------------------------------------------------------------------------
// prep: weight transpose+convert: w[k][n] f32 -> wt[n][k] bf16  (LDS 32x32 tile)
// blockIdx.z selects {wq,wk,wv,wo}
// ---------------------------------------------------------------------------
__global__ __launch_bounds__(256) void msa_transpose_w(
    const float* __restrict__ wq, const float* __restrict__ wk,
    const float* __restrict__ wv, const float* __restrict__ wo,
    bf16_t* __restrict__ wt_qkv, bf16_t* __restrict__ wt_o) {
  __shared__ float tile[32][33];
  const int a = blockIdx.z;
  const float* src = (a == 0) ? wq : (a == 1) ? wk : (a == 2) ? wv : wo;
  bf16_t* dst = (a < 3) ? (wt_qkv + (size_t)a * C_DIM * C_DIM) : wt_o;
  const int tx = threadIdx.x & 31, ty = threadIdx.x >> 5;
  const int bi = blockIdx.y * 32, bj = blockIdx.x * 32;
#pragma unroll
  for (int p = 0; p < 4; p++) {
    int r = p * 8 + ty;
    tile[r][tx] = src[(size_t)(bi + r) * C_DIM + bj + tx];
  }
  __syncthreads();
#pragma unroll
  for (int p = 0; p < 4; p++) {
    int r = p * 8 + ty;
    dst[(size_t)(bj + r) * C_DIM + bi + tx] = (bf16_t)tile[tx][r];
  }
}

// ---------------------------------------------------------------------------
// QKV GEMM: [8192 x 1024] @ Wt^T (Wt is [3072][1024]) -> scatter into
//   Q [b][h][t][d] (scaled by 1/8), K [b][h][t][d], Vt [b][h][d][t]  (bf16)
// 128x128 tile / block, 4 waves each 64x64, MFMA 16x16x32, direct-from-global.
// ---------------------------------------------------------------------------
__global__ __launch_bounds__(256) void msa_gemm_qkv(
    const bf16_t* __restrict__ xb, const bf16_t* __restrict__ wt,
    const float* __restrict__ bq, const float* __restrict__ bk,
    const float* __restrict__ bv,
    bf16_t* __restrict__ qo, bf16_t* __restrict__ ko, bf16_t* __restrict__ vto) {
  const int tid = threadIdx.x;
  const int w = tid >> 6, lane = tid & 63;
  const int lr = lane & 15, lg = lane >> 4;
  const int m0 = blockIdx.y * 128 + (w >> 1) * 64;
  const int n0 = blockIdx.x * 128 + (w & 1) * 64;

  f32x4 acc[4][4];
#pragma unroll
  for (int i = 0; i < 4; i++)
#pragma unroll
    for (int j = 0; j < 4; j++) acc[i][j] = (f32x4){0.f, 0.f, 0.f, 0.f};

  const bf16_t* ap = xb + (size_t)(m0 + lr) * C_DIM + lg * 8;
  const bf16_t* bp = wt + (size_t)(n0 + lr) * C_DIM + lg * 8;

  for (int k0 = 0; k0 < C_DIM; k0 += 32) {
    bf16x8 a[4], b[4];
#pragma unroll
    for (int i = 0; i < 4; i++) a[i] = *(const bf16x8*)(ap + (size_t)i * 16 * C_DIM + k0);
#pragma unroll
    for (int i = 0; i < 4; i++) b[i] = *(const bf16x8*)(bp + (size_t)i * 16 * C_DIM + k0);
#pragma unroll
    for (int mb = 0; mb < 4; mb++)
#pragma unroll
      for (int nb = 0; nb < 4; nb++)
        acc[mb][nb] = __builtin_amdgcn_mfma_f32_16x16x32_bf16(a[mb], b[nb], acc[mb][nb], 0, 0, 0);
  }

#pragma unroll
  for (int nb = 0; nb < 4; nb++) {
    const int n = n0 + nb * 16 + lr;
    const int g = n >> 10, c = n & 1023, h = c >> 6, d = c & 63;
    const float bias = (g == 0) ? bq[c] : (g == 1) ? bk[c] : bv[c];
#pragma unroll
    for (int mb = 0; mb < 4; mb++) {
#pragma unroll
      for (int r = 0; r < 4; r++) {
        const int m = m0 + mb * 16 + lg * 4 + r;
        const int bi = m >> 11, t = m & (T_SEQ - 1);
        float v = acc[mb][nb][r] + bias;
        if (g == 0)
          qo[(((size_t)bi * NH + h) * T_SEQ + t) * DH + d] = (bf16_t)(v * 0.125f);
        else if (g == 1)
          ko[(((size_t)bi * NH + h) * T_SEQ + t) * DH + d] = (bf16_t)v;
        else
          vto[(((size_t)bi * NH + h) * DH + d) * T_SEQ + t] = (bf16_t)v;
      }
    }
  }
}

// ---------------------------------------------------------------------------
// Flash attention (causal). Grid: (T/64, B*H). Block: 256 = 4 independent
// waves, each owns 16 query rows. KT=32 keys per iteration, online softmax
// wave-parallel via 16-lane shfl_xor reductions. P goes through padded
// wave-private LDS to convert C/D layout -> A-frag layout.
// ---------------------------------------------------------------------------
__global__ __launch_bounds__(256) void msa_attn(
    const bf16_t* __restrict__ Q, const bf16_t* __restrict__ K,
    const bf16_t* __restrict__ Vt, bf16_t* __restrict__ O) {
  __shared__ bf16_t plds[4][16][56];  // row stride 112B (16B aligned, 2-way banks)
  const int tid = threadIdx.x;
  const int w = tid >> 6, lane = tid & 63;
  const int lr = lane & 15, lg = lane >> 4;
  const int bh = blockIdx.y;
  const int q0 = blockIdx.x * 64 + w * 16;

  const bf16_t* Qh = Q + (size_t)bh * T_SEQ * DH;
  const bf16_t* Kh = K + (size_t)bh * T_SEQ * DH;
  const bf16_t* Vh = Vt + (size_t)bh * DH * T_SEQ;

  const bf16x8 qf0 = *(const bf16x8*)(Qh + (size_t)(q0 + lr) * DH + lg * 8);
  const bf16x8 qf1 = *(const bf16x8*)(Qh + (size_t)(q0 + lr) * DH + 32 + lg * 8);

  float m_run[4], l_run[4];
  f32x4 oacc[4];
#pragma unroll
  for (int r = 0; r < 4; r++) { m_run[r] = -INFINITY; l_run[r] = 0.f; }
#pragma unroll
  for (int i = 0; i < 4; i++) oacc[i] = (f32x4){0.f, 0.f, 0.f, 0.f};

  const float LOG2E = 1.44269504088896f;
  const int nkt = ((q0 + 15) >> 5) + 1;

  for (int kt = 0; kt < nkt; ++kt) {
    const int j0 = kt * 32;
    f32x4 s[2];
#pragma unroll
    for (int nb = 0; nb < 2; nb++) {
      const bf16_t* kp = Kh + (size_t)(j0 + nb * 16 + lr) * DH + lg * 8;
      bf16x8 k0v = *(const bf16x8*)(kp);
      bf16x8 k1v = *(const bf16x8*)(kp + 32);
      f32x4 z = (f32x4){0.f, 0.f, 0.f, 0.f};
      s[nb] = __builtin_amdgcn_mfma_f32_16x16x32_bf16(qf0, k0v, z, 0, 0, 0);
      s[nb] = __builtin_amdgcn_mfma_f32_16x16x32_bf16(qf1, k1v, s[nb], 0, 0, 0);
    }
    const bool full = (j0 + 31 <= q0);
    if (!full) {
#pragma unroll
      for (int nb = 0; nb < 2; nb++)
#pragma unroll
        for (int r = 0; r < 4; r++) {
          const int j = j0 + nb * 16 + lr;
          const int qq = q0 + lg * 4 + r;
          if (j > qq) s[nb][r] = -1e30f;
        }
    }
    float al[4];
#pragma unroll
    for (int r = 0; r < 4; r++) {
      float v = fmaxf(s[0][r], s[1][r]);
      v = fmaxf(v, __shfl_xor(v, 1));
      v = fmaxf(v, __shfl_xor(v, 2));
      v = fmaxf(v, __shfl_xor(v, 4));
      v = fmaxf(v, __shfl_xor(v, 8));
      const float mn = fmaxf(m_run[r], v);
      al[r] = exp2f((m_run[r] - mn) * LOG2E);
      m_run[r] = mn;
    }
    float p0[4], p1[4];
#pragma unroll
    for (int r = 0; r < 4; r++) {
      p0[r] = exp2f((s[0][r] - m_run[r]) * LOG2E);
      p1[r] = exp2f((s[1][r] - m_run[r]) * LOG2E);
      float sum = p0[r] + p1[r];
      sum += __shfl_xor(sum, 1);
      sum += __shfl_xor(sum, 2);
      sum += __shfl_xor(sum, 4);
      sum += __shfl_xor(sum, 8);
      l_run[r] = l_run[r] * al[r] + sum;
    }
#pragma unroll
    for (int nbd = 0; nbd < 4; nbd++)
#pragma unroll
      for (int r = 0; r < 4; r++) oacc[nbd][r] *= al[r];

#pragma unroll
    for (int r = 0; r < 4; r++) {
      plds[w][lg * 4 + r][lr] = (bf16_t)p0[r];
      plds[w][lg * 4 + r][16 + lr] = (bf16_t)p1[r];
    }
    asm volatile("s_waitcnt lgkmcnt(0)" ::: "memory");
    const bf16x8 pf = *(const bf16x8*)(&plds[w][lr][lg * 8]);
#pragma unroll
    for (int nbd = 0; nbd < 4; nbd++) {
      const bf16x8 vf =
          *(const bf16x8*)(Vh + (size_t)(nbd * 16 + lr) * T_SEQ + j0 + lg * 8);
      oacc[nbd] = __builtin_amdgcn_mfma_f32_16x16x32_bf16(pf, vf, oacc[nbd], 0, 0, 0);
    }
  }

  const int b = bh >> 4, h = bh & 15;
#pragma unroll
  for (int nbd = 0; nbd < 4; nbd++)
#pragma unroll
    for (int r = 0; r < 4; r++) {
      const int qq = q0 + lg * 4 + r;
      const float val = oacc[nbd][r] / l_run[r];
      O[((size_t)b * T_SEQ + qq) * C_DIM + h * DH + nbd * 16 + lr] = (bf16_t)val;
    }
}

// ---------------------------------------------------------------------------
// Output projection: attn_out[8192x1024] bf16 @ wo -> f32 out (+bo)
// ---------------------------------------------------------------------------
__global__ __launch_bounds__(256) void msa_gemm_out(
    const bf16_t* __restrict__ ab, const bf16_t* __restrict__ wt,
    const float* __restrict__ bo, float* __restrict__ out) {
  const int tid = threadIdx.x;
  const int w = tid >> 6, lane = tid & 63;
  const int lr = lane & 15, lg = lane >> 4;
  const int m0 = blockIdx.y * 128 + (w >> 1) * 64;
  const int n0 = blockIdx.x * 128 + (w & 1) * 64;

  f32x4 acc[4][4];
#pragma unroll
  for (int i = 0; i < 4; i++)
#pragma unroll
    for (int j = 0; j < 4; j++) acc[i][j] = (f32x4){0.f, 0.f, 0.f, 0.f};

  const bf16_t* ap = ab + (size_t)(m0 + lr) * C_DIM + lg * 8;
  const bf16_t* bp = wt + (size_t)(n0 + lr) * C_DIM + lg * 8;

  for (int k0 = 0; k0 < C_DIM; k0 += 32) {
    bf16x8 a[4], b[4];
#pragma unroll
    for (int i = 0; i < 4; i++) a[i] = *(const bf16x8*)(ap + (size_t)i * 16 * C_DIM + k0);
#pragma unroll
    for (int i = 0; i < 4; i++) b[i] = *(const bf16x8*)(bp + (size_t)i * 16 * C_DIM + k0);
#pragma unroll
    for (int mb = 0; mb < 4; mb++)
#pragma unroll
      for (int nb = 0; nb < 4; nb++)
        acc[mb][nb] = __builtin_amdgcn_mfma_f32_16x16x32_bf16(a[mb], b[nb], acc[mb][nb], 0, 0, 0);
  }

#pragma unroll
  for (int nb = 0; nb < 4; nb++) {
    const int n = n0 + nb * 16 + lr;
    const float bias = bo[n];
#pragma unroll
    for (int mb = 0; mb < 4; mb++) {
#pragma unroll
      for (int r = 0; r < 4; r++) {
        const int m = m0 + mb * 16 + lg * 4 + r;
        out[(size_t)m * C_DIM + n] = acc[mb][nb][r] + bias;
      }
    }
  }
}

// ---------------------------------------------------------------------------
// launch
// ---------------------------------------------------------------------------
extern "C" void kernel_launch(void* const* d_in, const int* in_sizes, int n_in,
                              void* d_out, int out_size, void* d_ws, size_t ws_size,
                              hipStream_t stream) {
  const float* x  = (const float*)d_in[0];
  // d_in[1] = mask (causal; recomputed analytically, not read)
  const float* wq = (const float*)d_in[2];
  const float* bq = (const float*)d_in[3];
  const float* wk = (const float*)d_in[4];
  const float* bk = (const float*)d_in[5];
  const float* wv = (const float*)d_in[6];
  const float* bv = (const float*)d_in[7];
  const float* wo = (const float*)d_in[8];
  const float* bo = (const float*)d_in[9];

  char* ws = (char*)d_ws;
  // ws layout (72 MiB total):
  //   [0,16M)   xb (x in bf16)  -- later reused as attn_out (same shape)
  //   [16M,22M) wt_qkv  (3 x [1024][1024] bf16, transposed)
  //   [22M,24M) wt_o
  //   [24M,40M) Q   [b][h][t][d]
  //   [40M,56M) K   [b][h][t][d]
  //   [56M,72M) Vt  [b][h][d][t]
  bf16_t* xb     = (bf16_t*)(ws);
  bf16_t* wt_qkv = (bf16_t*)(ws + (16ull << 20));
  bf16_t* wt_o   = (bf16_t*)(ws + (22ull << 20));
  bf16_t* qb     = (bf16_t*)(ws + (24ull << 20));
  bf16_t* kb     = (bf16_t*)(ws + (40ull << 20));
  bf16_t* vtb    = (bf16_t*)(ws + (56ull << 20));
  bf16_t* attn_o = xb;  // alias: xb dead after QKV GEMM

  const int n4 = M_TOK * C_DIM / 4;
  msa_cvt_x<<<n4 / 256, 256, 0, stream>>>(x, xb, n4);
  msa_transpose_w<<<dim3(32, 32, 4), 256, 0, stream>>>(wq, wk, wv, wo, wt_qkv, wt_o);
  msa_gemm_qkv<<<dim3(24, 64), 256, 0, stream>>>(xb, wt_qkv, bq, bk, bv, qb, kb, vtb);
  msa_attn<<<dim3(T_SEQ / 64, BATCH * NH), 256, 0, stream>>>(qb, kb, vtb, attn_o);
  msa_gemm_out<<<dim3(8, 64), 256, 0, stream>>>(attn_o, wt_o, bo, (float*)d_out);
}

// Round 2
// 510.012 us; speedup vs baseline: 1.4331x; 1.4331x over previous
//
#include <hip/hip_runtime.h>

typedef __bf16 bf16_t;
typedef bf16_t bf16x8 __attribute__((ext_vector_type(8)));
typedef bf16_t bf16x4 __attribute__((ext_vector_type(4)));
typedef float  f32x4  __attribute__((ext_vector_type(4)));
typedef float  f32x16 __attribute__((ext_vector_type(16)));
typedef unsigned int u32;
typedef u32 u32x4 __attribute__((ext_vector_type(4)));

#define T_SEQ 2048
#define C_DIM 1024
#define NH    16
#define DH    64
#define BATCH 4
#define M_TOK (BATCH * T_SEQ)   // 8192

// Q pre-scale: 1/sqrt(64) * log2(e)  -> softmax computed in exp2 domain
#define Q_SCALE 0.1803368801111137f

// ---------------------------------------------------------------------------
// prep: x f32 -> bf16 (vectorized float4 -> bf16x4)
// ---------------------------------------------------------------------------
__global__ __launch_bounds__(256) void msa_cvt_x(const float* __restrict__ x,
                                                 bf16_t* __restrict__ xb, int n4) {
  int i = blockIdx.x * 256 + threadIdx.x;
  if (i < n4) {
    const float4 v = ((const float4*)x)[i];
    bf16x4 o;
    o[0] = (bf16_t)v.x; o[1] = (bf16_t)v.y; o[2] = (bf16_t)v.z; o[3] = (bf16_t)v.w;
    ((bf16x4*)xb)[i] = o;
  }
}

// ---------------------------------------------------------------------------
// prep: weight transpose+convert: w[k][n] f32 -> wt[n][k] bf16  (LDS 32x32 tile)
// ---------------------------------------------------------------------------
__global__ __launch_bounds__(256) void msa_transpose_w(
    const float* __restrict__ wq, const float* __restrict__ wk,
    const float* __restrict__ wv, const float* __restrict__ wo,
    bf16_t* __restrict__ wt_qkv, bf16_t* __restrict__ wt_o) {
  __shared__ float tile[32][33];
  const int a = blockIdx.z;
  const float* src = (a == 0) ? wq : (a == 1) ? wk : (a == 2) ? wv : wo;
  bf16_t* dst = (a < 3) ? (wt_qkv + (size_t)a * C_DIM * C_DIM) : wt_o;
  const int tx = threadIdx.x & 31, ty = threadIdx.x >> 5;
  const int bi = blockIdx.y * 32, bj = blockIdx.x * 32;
#pragma unroll
  for (int p = 0; p < 4; p++) {
    int r = p * 8 + ty;
    tile[r][tx] = src[(size_t)(bi + r) * C_DIM + bj + tx];
  }
  __syncthreads();
#pragma unroll
  for (int p = 0; p < 4; p++) {
    int r = p * 8 + ty;
    dst[(size_t)(bj + r) * C_DIM + bi + tx] = (bf16_t)tile[tx][r];
  }
}

// ---------------------------------------------------------------------------
// QKV GEMM -> Q (scaled by Q_SCALE), K, Vt(bf16, [b][h][d][t])
// ---------------------------------------------------------------------------
__global__ __launch_bounds__(256) void msa_gemm_qkv(
    const bf16_t* __restrict__ xb, const bf16_t* __restrict__ wt,
    const float* __restrict__ bq, const float* __restrict__ bk,
    const float* __restrict__ bv,
    bf16_t* __restrict__ qo, bf16_t* __restrict__ ko, bf16_t* __restrict__ vto) {
  const int tid = threadIdx.x;
  const int w = tid >> 6, lane = tid & 63;
  const int lr = lane & 15, lg = lane >> 4;
  const int m0 = blockIdx.y * 128 + (w >> 1) * 64;
  const int n0 = blockIdx.x * 128 + (w & 1) * 64;

  f32x4 acc[4][4];
#pragma unroll
  for (int i = 0; i < 4; i++)
#pragma unroll
    for (int j = 0; j < 4; j++) acc[i][j] = (f32x4){0.f, 0.f, 0.f, 0.f};

  const bf16_t* ap = xb + (size_t)(m0 + lr) * C_DIM + lg * 8;
  const bf16_t* bp = wt + (size_t)(n0 + lr) * C_DIM + lg * 8;

  for (int k0 = 0; k0 < C_DIM; k0 += 32) {
    bf16x8 a[4], b[4];
#pragma unroll
    for (int i = 0; i < 4; i++) a[i] = *(const bf16x8*)(ap + (size_t)i * 16 * C_DIM + k0);
#pragma unroll
    for (int i = 0; i < 4; i++) b[i] = *(const bf16x8*)(bp + (size_t)i * 16 * C_DIM + k0);
#pragma unroll
    for (int mb = 0; mb < 4; mb++)
#pragma unroll
      for (int nb = 0; nb < 4; nb++)
        acc[mb][nb] = __builtin_amdgcn_mfma_f32_16x16x32_bf16(a[mb], b[nb], acc[mb][nb], 0, 0, 0);
  }

#pragma unroll
  for (int nb = 0; nb < 4; nb++) {
    const int n = n0 + nb * 16 + lr;
    const int g = n >> 10, c = n & 1023, h = c >> 6, d = c & 63;
    const float bias = (g == 0) ? bq[c] : (g == 1) ? bk[c] : bv[c];
#pragma unroll
    for (int mb = 0; mb < 4; mb++) {
#pragma unroll
      for (int r = 0; r < 4; r++) {
        const int m = m0 + mb * 16 + lg * 4 + r;
        const int bi = m >> 11, t = m & (T_SEQ - 1);
        float v = acc[mb][nb][r] + bias;
        if (g == 0)
          qo[(((size_t)bi * NH + h) * T_SEQ + t) * DH + d] = (bf16_t)(v * Q_SCALE);
        else if (g == 1)
          ko[(((size_t)bi * NH + h) * T_SEQ + t) * DH + d] = (bf16_t)v;
        else
          vto[(((size_t)bi * NH + h) * DH + d) * T_SEQ + t] = (bf16_t)v;
      }
    }
  }
}

// ---------------------------------------------------------------------------
// Flash attention (causal), m214-style swapped 32x32 MFMA structure.
// Grid: (T/128, B*H), block 256 = 4 independent waves, 32 queries per wave.
// S^T = mfma(A=K, B=Q)  -> lane holds 16 of 32 key-scores for q = lane&31.
// Softmax: in-register tree + one shfl_xor(32). P redistributed to B-frag
// via 8 pack + 8 shfl_xor(32) + selects. O^T = mfma(A=V^T, B=P) -> q stays
// lane-resident, so rescale/normalize are per-lane scalars. No LDS.
// ---------------------------------------------------------------------------
__global__ __launch_bounds__(256, 3) void msa_attn32(
    const bf16_t* __restrict__ Q, const bf16_t* __restrict__ K,
    const bf16_t* __restrict__ Vt, bf16_t* __restrict__ O) {
  const int tid = threadIdx.x;
  const int w = tid >> 6;
  const int lane = tid & 63;
  const int l31 = lane & 31;
  const int hi = lane >> 5;
  const int bh = blockIdx.y;
  const int qt = gridDim.x - 1 - blockIdx.x;  // longest blocks dispatch first
  const int q0 = qt * 128 + w * 32;

  const bf16_t* Qh = Q + (size_t)bh * T_SEQ * DH;
  const bf16_t* Kh = K + (size_t)bh * T_SEQ * DH;
  const bf16_t* Vh = Vt + (size_t)bh * DH * T_SEQ;

  // Q fragments (B operand): lane holds Q[q0+l31][dc*16 + hi*8 + i]
  bf16x8 qf[4];
#pragma unroll
  for (int dc = 0; dc < 4; dc++)
    qf[dc] = *(const bf16x8*)(Qh + (size_t)(q0 + l31) * DH + dc * 16 + hi * 8);

  f32x16 oacc0, oacc1;
#pragma unroll
  for (int r = 0; r < 16; r++) { oacc0[r] = 0.f; oacc1[r] = 0.f; }
  float m_run = -1e30f, l_run = 0.f;

  const int ndiag = q0 >> 5;
  for (int kt = 0; kt <= ndiag; ++kt) {
    const int j0 = kt * 32;

    // --- S^T = K . Q^T  (accumulate over 4 d-chunks of 16) ---
    f32x16 s;
#pragma unroll
    for (int r = 0; r < 16; r++) s[r] = 0.f;
#pragma unroll
    for (int dc = 0; dc < 4; dc++) {
      const bf16x8 kf =
          *(const bf16x8*)(Kh + (size_t)(j0 + l31) * DH + dc * 16 + hi * 8);
      s = __builtin_amdgcn_mfma_f32_32x32x16_bf16(kf, qf[dc], s, 0, 0, 0);
    }

    // --- causal mask (diagonal tile only): jrow > q-col -> -inf ---
    if (kt == ndiag) {
#pragma unroll
      for (int r = 0; r < 16; r++) {
        const int jrow = (r & 3) + 8 * (r >> 2) + 4 * hi;
        if (jrow > l31) s[r] = -1e30f;
      }
    }

    // --- row max: in-register tree + cross-half swap ---
    float m01 = fmaxf(fmaxf(s[0], s[1]), fmaxf(s[2], s[3]));
    float m23 = fmaxf(fmaxf(s[4], s[5]), fmaxf(s[6], s[7]));
    float m45 = fmaxf(fmaxf(s[8], s[9]), fmaxf(s[10], s[11]));
    float m67 = fmaxf(fmaxf(s[12], s[13]), fmaxf(s[14], s[15]));
    float mt = fmaxf(fmaxf(m01, m23), fmaxf(m45, m67));
    mt = fmaxf(mt, __shfl_xor(mt, 32));
    const float mnew = fmaxf(m_run, mt);
    const float al = __builtin_amdgcn_exp2f(m_run - mnew);
    m_run = mnew;

    // --- exp + row sum ---
    float p[16];
#pragma unroll
    for (int r = 0; r < 16; r++) p[r] = __builtin_amdgcn_exp2f(s[r] - mnew);
    float a0 = (p[0] + p[1]) + (p[2] + p[3]);
    float a1 = (p[4] + p[5]) + (p[6] + p[7]);
    float a2 = (p[8] + p[9]) + (p[10] + p[11]);
    float a3 = (p[12] + p[13]) + (p[14] + p[15]);
    float lt = (a0 + a1) + (a2 + a3);
    lt += __shfl_xor(lt, 32);
    l_run = l_run * al + lt;

    // --- rescale O ---
#pragma unroll
    for (int r = 0; r < 16; r++) { oacc0[r] *= al; oacc1[r] *= al; }

    // --- pack P to bf16 pairs, redistribute across lane halves ---
    u32 pk8[8];
#pragma unroll
    for (int i = 0; i < 8; i++) {
      const unsigned short lo = __builtin_bit_cast(unsigned short, (bf16_t)p[2 * i]);
      const unsigned short hh = __builtin_bit_cast(unsigned short, (bf16_t)p[2 * i + 1]);
      pk8[i] = ((u32)hh << 16) | (u32)lo;
    }
    u32 xs[8];
#pragma unroll
    for (int i = 0; i < 8; i++) xs[i] = (u32)__shfl_xor((int)pk8[i], 32);

    u32x4 f0, f1;
    f0[0] = hi ? xs[2] : pk8[0];
    f0[1] = hi ? xs[3] : pk8[1];
    f0[2] = hi ? pk8[2] : xs[0];
    f0[3] = hi ? pk8[3] : xs[1];
    f1[0] = hi ? xs[6] : pk8[4];
    f1[1] = hi ? xs[7] : pk8[5];
    f1[2] = hi ? pk8[6] : xs[4];
    f1[3] = hi ? pk8[7] : xs[5];
    const bf16x8 pa0 = __builtin_bit_cast(bf16x8, f0);
    const bf16x8 pa1 = __builtin_bit_cast(bf16x8, f1);

    // --- O^T += V^T . P^T : A = V^T frag, B = P frag ---
#pragma unroll
    for (int c = 0; c < 2; c++) {
      const bf16x8 pa = c ? pa1 : pa0;
      const bf16x8 vf0 =
          *(const bf16x8*)(Vh + (size_t)(l31)*T_SEQ + j0 + c * 16 + hi * 8);
      const bf16x8 vf1 =
          *(const bf16x8*)(Vh + (size_t)(32 + l31) * T_SEQ + j0 + c * 16 + hi * 8);
      oacc0 = __builtin_amdgcn_mfma_f32_32x32x16_bf16(vf0, pa, oacc0, 0, 0, 0);
      oacc1 = __builtin_amdgcn_mfma_f32_32x32x16_bf16(vf1, pa, oacc1, 0, 0, 0);
    }
  }

  // --- normalize + store (bf16 pairs, 4B stores) ---
  const int b = bh >> 4, h = bh & 15;
  const float inv = 1.0f / l_run;
  bf16_t* orow = O + ((size_t)b * T_SEQ + q0 + l31) * C_DIM + h * DH;
#pragma unroll
  for (int db = 0; db < 2; db++) {
#pragma unroll
    for (int r = 0; r < 16; r += 2) {
      const int d = db * 32 + (r & 3) + 8 * (r >> 2) + 4 * hi;
      const float v0 = (db ? oacc1[r] : oacc0[r]) * inv;
      const float v1 = (db ? oacc1[r + 1] : oacc0[r + 1]) * inv;
      const unsigned short b0 = __builtin_bit_cast(unsigned short, (bf16_t)v0);
      const unsigned short b1 = __builtin_bit_cast(unsigned short, (bf16_t)v1);
      *reinterpret_cast<u32*>(orow + d) = ((u32)b1 << 16) | (u32)b0;
    }
  }
}

// ---------------------------------------------------------------------------
// Output projection: attn_out[8192x1024] bf16 @ wo -> f32 out (+bo)
// ---------------------------------------------------------------------------
__global__ __launch_bounds__(256) void msa_gemm_out(
    const bf16_t* __restrict__ ab, const bf16_t* __restrict__ wt,
    const float* __restrict__ bo, float* __restrict__ out) {
  const int tid = threadIdx.x;
  const int w = tid >> 6, lane = tid & 63;
  const int lr = lane & 15, lg = lane >> 4;
  const int m0 = blockIdx.y * 128 + (w >> 1) * 64;
  const int n0 = blockIdx.x * 128 + (w & 1) * 64;

  f32x4 acc[4][4];
#pragma unroll
  for (int i = 0; i < 4; i++)
#pragma unroll
    for (int j = 0; j < 4; j++) acc[i][j] = (f32x4){0.f, 0.f, 0.f, 0.f};

  const bf16_t* ap = ab + (size_t)(m0 + lr) * C_DIM + lg * 8;
  const bf16_t* bp = wt + (size_t)(n0 + lr) * C_DIM + lg * 8;

  for (int k0 = 0; k0 < C_DIM; k0 += 32) {
    bf16x8 a[4], b[4];
#pragma unroll
    for (int i = 0; i < 4; i++) a[i] = *(const bf16x8*)(ap + (size_t)i * 16 * C_DIM + k0);
#pragma unroll
    for (int i = 0; i < 4; i++) b[i] = *(const bf16x8*)(bp + (size_t)i * 16 * C_DIM + k0);
#pragma unroll
    for (int mb = 0; mb < 4; mb++)
#pragma unroll
      for (int nb = 0; nb < 4; nb++)
        acc[mb][nb] = __builtin_amdgcn_mfma_f32_16x16x32_bf16(a[mb], b[nb], acc[mb][nb], 0, 0, 0);
  }

#pragma unroll
  for (int nb = 0; nb < 4; nb++) {
    const int n = n0 + nb * 16 + lr;
    const float bias = bo[n];
#pragma unroll
    for (int mb = 0; mb < 4; mb++) {
#pragma unroll
      for (int r = 0; r < 4; r++) {
        const int m = m0 + mb * 16 + lg * 4 + r;
        out[(size_t)m * C_DIM + n] = acc[mb][nb][r] + bias;
      }
    }
  }
}

// ---------------------------------------------------------------------------
// launch
// ---------------------------------------------------------------------------
extern "C" void kernel_launch(void* const* d_in, const int* in_sizes, int n_in,
                              void* d_out, int out_size, void* d_ws, size_t ws_size,
                              hipStream_t stream) {
  const float* x  = (const float*)d_in[0];
  // d_in[1] = mask (causal; recomputed analytically, not read)
  const float* wq = (const float*)d_in[2];
  const float* bq = (const float*)d_in[3];
  const float* wk = (const float*)d_in[4];
  const float* bk = (const float*)d_in[5];
  const float* wv = (const float*)d_in[6];
  const float* bv = (const float*)d_in[7];
  const float* wo = (const float*)d_in[8];
  const float* bo = (const float*)d_in[9];

  char* ws = (char*)d_ws;
  bf16_t* xb     = (bf16_t*)(ws);
  bf16_t* wt_qkv = (bf16_t*)(ws + (16ull << 20));
  bf16_t* wt_o   = (bf16_t*)(ws + (22ull << 20));
  bf16_t* qb     = (bf16_t*)(ws + (24ull << 20));
  bf16_t* kb     = (bf16_t*)(ws + (40ull << 20));
  bf16_t* vtb    = (bf16_t*)(ws + (56ull << 20));
  bf16_t* attn_o = xb;  // alias: xb dead after QKV GEMM

  const int n4 = M_TOK * C_DIM / 4;
  msa_cvt_x<<<n4 / 256, 256, 0, stream>>>(x, xb, n4);
  msa_transpose_w<<<dim3(32, 32, 4), 256, 0, stream>>>(wq, wk, wv, wo, wt_qkv, wt_o);
  msa_gemm_qkv<<<dim3(24, 64), 256, 0, stream>>>(xb, wt_qkv, bq, bk, bv, qb, kb, vtb);
  msa_attn32<<<dim3(T_SEQ / 128, BATCH * NH), 256, 0, stream>>>(qb, kb, vtb, attn_o);
  msa_gemm_out<<<dim3(8, 64), 256, 0, stream>>>(attn_o, wt_o, bo, (float*)d_out);
}

// Round 3
// 320.106 us; speedup vs baseline: 2.2833x; 1.5933x over previous
//
#include <hip/hip_runtime.h>

typedef __bf16 bf16_t;
typedef bf16_t bf16x8 __attribute__((ext_vector_type(8)));
typedef bf16_t bf16x4 __attribute__((ext_vector_type(4)));
typedef float  f32x4  __attribute__((ext_vector_type(4)));
typedef float  f32x16 __attribute__((ext_vector_type(16)));
typedef unsigned int u32;
typedef u32 u32x4 __attribute__((ext_vector_type(4)));

#define T_SEQ 2048
#define C_DIM 1024
#define NH    16
#define DH    64
#define BATCH 4
#define M_TOK (BATCH * T_SEQ)   // 8192

// Q pre-scale: 1/sqrt(64) * log2(e)  -> softmax computed in exp2 domain
#define Q_SCALE 0.1803368801111137f
#define DEFER_THR 8.0f

#define AS1 __attribute__((address_space(1)))
#define AS3 __attribute__((address_space(3)))

// async global->LDS, 16B per lane. LDS dest must be linear in lane order
// (wave-uniform base + lane*16): pass per-thread l = base + tid*16B.
__device__ __forceinline__ void gld_lds16(const bf16_t* g, bf16_t* l) {
  __builtin_amdgcn_global_load_lds(
      (const AS1 u32*)(uintptr_t)g,
      (AS3 u32*)(u32)(uintptr_t)l, 16, 0, 0);
}

// ---------------------------------------------------------------------------
// prep: x f32 -> bf16
// ---------------------------------------------------------------------------
__global__ __launch_bounds__(256) void msa_cvt_x(const float* __restrict__ x,
                                                 bf16_t* __restrict__ xb, int n4) {
  int i = blockIdx.x * 256 + threadIdx.x;
  if (i < n4) {
    const float4 v = ((const float4*)x)[i];
    bf16x4 o;
    o[0] = (bf16_t)v.x; o[1] = (bf16_t)v.y; o[2] = (bf16_t)v.z; o[3] = (bf16_t)v.w;
    ((bf16x4*)xb)[i] = o;
  }
}

// ---------------------------------------------------------------------------
// prep: weight transpose+convert: w[k][n] f32 -> wt[n][k] bf16
// ---------------------------------------------------------------------------
__global__ __launch_bounds__(256) void msa_transpose_w(
    const float* __restrict__ wq, const float* __restrict__ wk,
    const float* __restrict__ wv, const float* __restrict__ wo,
    bf16_t* __restrict__ wt_qkv, bf16_t* __restrict__ wt_o) {
  __shared__ float tile[32][33];
  const int a = blockIdx.z;
  const float* src = (a == 0) ? wq : (a == 1) ? wk : (a == 2) ? wv : wo;
  bf16_t* dst = (a < 3) ? (wt_qkv + (size_t)a * C_DIM * C_DIM) : wt_o;
  const int tx = threadIdx.x & 31, ty = threadIdx.x >> 5;
  const int bi = blockIdx.y * 32, bj = blockIdx.x * 32;
#pragma unroll
  for (int p = 0; p < 4; p++) {
    int r = p * 8 + ty;
    tile[r][tx] = src[(size_t)(bi + r) * C_DIM + bj + tx];
  }
  __syncthreads();
#pragma unroll
  for (int p = 0; p < 4; p++) {
    int r = p * 8 + ty;
    dst[(size_t)(bj + r) * C_DIM + bi + tx] = (bf16_t)tile[tx][r];
  }
}

// ---------------------------------------------------------------------------
// QKV GEMM, m97 structure: 128x128 tile, BK=32, global_load_lds staging,
// 2-barrier K-loop, 4 waves x (64x64). Epilogue scatters Q(scaled)/K/Vt.
// ---------------------------------------------------------------------------
__global__ __launch_bounds__(256) void msa_gemm_qkv(
    const bf16_t* __restrict__ xb, const bf16_t* __restrict__ wt,
    const float* __restrict__ bq, const float* __restrict__ bk,
    const float* __restrict__ bv,
    bf16_t* __restrict__ qo, bf16_t* __restrict__ ko, bf16_t* __restrict__ vto) {
  __shared__ bf16_t lA[128 * 32];
  __shared__ bf16_t lB[128 * 32];
  const int tid = threadIdx.x;
  const int w = tid >> 6, lane = tid & 63;
  const int lr = lane & 15, lg = lane >> 4;
  const int m0 = blockIdx.y * 128;
  const int n0 = blockIdx.x * 128;
  const int wm = (w >> 1) * 64, wn = (w & 1) * 64;

  // staging: thread tid covers elements [tid*8, tid*8+8) of the row-major
  // [128][32] tile halves; source row = tid/4, col = (tid%4)*8.
  const int srow = tid >> 2, scol = (tid & 3) * 8;
  const bf16_t* ga = xb + (size_t)(m0 + srow) * C_DIM + scol;
  const bf16_t* gb = wt + (size_t)(n0 + srow) * C_DIM + scol;

  f32x4 acc[4][4];
#pragma unroll
  for (int i = 0; i < 4; i++)
#pragma unroll
    for (int j = 0; j < 4; j++) acc[i][j] = (f32x4){0.f, 0.f, 0.f, 0.f};

  for (int k0 = 0; k0 < C_DIM; k0 += 32) {
    gld_lds16(ga + k0, &lA[tid * 8]);
    gld_lds16(ga + (size_t)64 * C_DIM + k0, &lA[2048 + tid * 8]);
    gld_lds16(gb + k0, &lB[tid * 8]);
    gld_lds16(gb + (size_t)64 * C_DIM + k0, &lB[2048 + tid * 8]);
    __syncthreads();
    bf16x8 a[4], b[4];
#pragma unroll
    for (int mb = 0; mb < 4; mb++)
      a[mb] = *(const bf16x8*)&lA[(wm + mb * 16 + lr) * 32 + lg * 8];
#pragma unroll
    for (int nb = 0; nb < 4; nb++)
      b[nb] = *(const bf16x8*)&lB[(wn + nb * 16 + lr) * 32 + lg * 8];
#pragma unroll
    for (int mb = 0; mb < 4; mb++)
#pragma unroll
      for (int nb = 0; nb < 4; nb++)
        acc[mb][nb] = __builtin_amdgcn_mfma_f32_16x16x32_bf16(a[mb], b[nb], acc[mb][nb], 0, 0, 0);
    __syncthreads();
  }

#pragma unroll
  for (int nb = 0; nb < 4; nb++) {
    const int n = n0 + wn + nb * 16 + lr;
    const int g = n >> 10, c = n & 1023, h = c >> 6, d = c & 63;
    const float bias = (g == 0) ? bq[c] : (g == 1) ? bk[c] : bv[c];
#pragma unroll
    for (int mb = 0; mb < 4; mb++) {
#pragma unroll
      for (int r = 0; r < 4; r++) {
        const int m = m0 + wm + mb * 16 + lg * 4 + r;
        const int bi = m >> 11, t = m & (T_SEQ - 1);
        float v = acc[mb][nb][r] + bias;
        if (g == 0)
          qo[(((size_t)bi * NH + h) * T_SEQ + t) * DH + d] = (bf16_t)(v * Q_SCALE);
        else if (g == 1)
          ko[(((size_t)bi * NH + h) * T_SEQ + t) * DH + d] = (bf16_t)v;
        else
          vto[(((size_t)bi * NH + h) * DH + d) * T_SEQ + t] = (bf16_t)v;
      }
    }
  }
}

// ---------------------------------------------------------------------------
// Flash attention (causal), swapped 32x32 MFMA, 1-wave blocks.
// Grid: (64, B*H); block = 64 threads = 1 wave owning 32 queries
// (t = 63 - blockIdx.x: longest tiles dispatch first, backfill balances).
// K register-prefetch one tile ahead; V issued at iteration top; defer-max
// (THR=8) skips the O-rescale on most tiles. No LDS.
// ---------------------------------------------------------------------------
__global__ __launch_bounds__(64) void msa_attn32(
    const bf16_t* __restrict__ Q, const bf16_t* __restrict__ K,
    const bf16_t* __restrict__ Vt, bf16_t* __restrict__ O) {
  const int lane = threadIdx.x;
  const int l31 = lane & 31;
  const int hi = lane >> 5;
  const int bh = blockIdx.y;
  const int t = (int)gridDim.x - 1 - (int)blockIdx.x;  // 63..0, long first
  const int q0 = t * 32;

  const bf16_t* Qh = Q + (size_t)bh * T_SEQ * DH;
  const bf16_t* Kh = K + (size_t)bh * T_SEQ * DH;
  const bf16_t* Vh = Vt + (size_t)bh * DH * T_SEQ;

  bf16x8 qf[4];
#pragma unroll
  for (int dc = 0; dc < 4; dc++)
    qf[dc] = *(const bf16x8*)(Qh + (size_t)(q0 + l31) * DH + dc * 16 + hi * 8);

  f32x16 oacc0, oacc1;
#pragma unroll
  for (int r = 0; r < 16; r++) { oacc0[r] = 0.f; oacc1[r] = 0.f; }
  float m_run = -1e30f, l_run = 0.f;

  // preload K tile 0
  bf16x8 kf[4];
#pragma unroll
  for (int dc = 0; dc < 4; dc++)
    kf[dc] = *(const bf16x8*)(Kh + (size_t)l31 * DH + dc * 16 + hi * 8);

  for (int kt = 0; kt <= t; ++kt) {
    const int j0 = kt * 32;
    const int j0n = (kt < t) ? j0 + 32 : 0;

    // prefetch next K tile + this tile's V (consumed after softmax)
    bf16x8 kn[4];
#pragma unroll
    for (int dc = 0; dc < 4; dc++)
      kn[dc] = *(const bf16x8*)(Kh + (size_t)(j0n + l31) * DH + dc * 16 + hi * 8);
    bf16x8 vf[2][2];
#pragma unroll
    for (int rb = 0; rb < 2; rb++)
#pragma unroll
      for (int c = 0; c < 2; c++)
        vf[rb][c] = *(const bf16x8*)(Vh + (size_t)(rb * 32 + l31) * T_SEQ + j0 + c * 16 + hi * 8);

    // --- S^T = K . Q^T ---
    f32x16 s;
#pragma unroll
    for (int r = 0; r < 16; r++) s[r] = 0.f;
#pragma unroll
    for (int dc = 0; dc < 4; dc++)
      s = __builtin_amdgcn_mfma_f32_32x32x16_bf16(kf[dc], qf[dc], s, 0, 0, 0);

    // --- causal mask (diagonal tile only) ---
    if (kt == t) {
#pragma unroll
      for (int r = 0; r < 16; r++) {
        const int jrow = (r & 3) + 8 * (r >> 2) + 4 * hi;
        if (jrow > l31) s[r] = -1e30f;
      }
    }

    // --- tile max ---
    float m01 = fmaxf(fmaxf(s[0], s[1]), fmaxf(s[2], s[3]));
    float m23 = fmaxf(fmaxf(s[4], s[5]), fmaxf(s[6], s[7]));
    float m45 = fmaxf(fmaxf(s[8], s[9]), fmaxf(s[10], s[11]));
    float m67 = fmaxf(fmaxf(s[12], s[13]), fmaxf(s[14], s[15]));
    float mt = fmaxf(fmaxf(m01, m23), fmaxf(m45, m67));
    mt = fmaxf(mt, __shfl_xor(mt, 32));

    // --- defer-max: rescale only when the max grew materially ---
    if (__any(mt > m_run + DEFER_THR)) {
      const float mnew = fmaxf(m_run, mt);
      const float al = __builtin_amdgcn_exp2f(m_run - mnew);
      m_run = mnew;
      l_run *= al;
#pragma unroll
      for (int r = 0; r < 16; r++) { oacc0[r] *= al; oacc1[r] *= al; }
    }

    // --- exp (in place) + row sum ---
#pragma unroll
    for (int r = 0; r < 16; r++) s[r] = __builtin_amdgcn_exp2f(s[r] - m_run);
    {
      float a0 = (s[0] + s[1]) + (s[2] + s[3]);
      float a1 = (s[4] + s[5]) + (s[6] + s[7]);
      float a2 = (s[8] + s[9]) + (s[10] + s[11]);
      float a3 = (s[12] + s[13]) + (s[14] + s[15]);
      float lt = (a0 + a1) + (a2 + a3);
      lt += __shfl_xor(lt, 32);
      l_run += lt;
    }

    // --- pack P to bf16 pairs, redistribute across lane halves ---
    u32 pk8[8];
#pragma unroll
    for (int i = 0; i < 8; i++) {
      const unsigned short lo = __builtin_bit_cast(unsigned short, (bf16_t)s[2 * i]);
      const unsigned short hh = __builtin_bit_cast(unsigned short, (bf16_t)s[2 * i + 1]);
      pk8[i] = ((u32)hh << 16) | (u32)lo;
    }
    u32 xs[8];
#pragma unroll
    for (int i = 0; i < 8; i++) xs[i] = (u32)__shfl_xor((int)pk8[i], 32);

    u32x4 f0, f1;
    f0[0] = hi ? xs[2] : pk8[0];
    f0[1] = hi ? xs[3] : pk8[1];
    f0[2] = hi ? pk8[2] : xs[0];
    f0[3] = hi ? pk8[3] : xs[1];
    f1[0] = hi ? xs[6] : pk8[4];
    f1[1] = hi ? xs[7] : pk8[5];
    f1[2] = hi ? pk8[6] : xs[4];
    f1[3] = hi ? pk8[7] : xs[5];
    const bf16x8 pa0 = __builtin_bit_cast(bf16x8, f0);
    const bf16x8 pa1 = __builtin_bit_cast(bf16x8, f1);

    // --- O^T += V^T . P ---
    oacc0 = __builtin_amdgcn_mfma_f32_32x32x16_bf16(vf[0][0], pa0, oacc0, 0, 0, 0);
    oacc1 = __builtin_amdgcn_mfma_f32_32x32x16_bf16(vf[1][0], pa0, oacc1, 0, 0, 0);
    oacc0 = __builtin_amdgcn_mfma_f32_32x32x16_bf16(vf[0][1], pa1, oacc0, 0, 0, 0);
    oacc1 = __builtin_amdgcn_mfma_f32_32x32x16_bf16(vf[1][1], pa1, oacc1, 0, 0, 0);

    // rotate K prefetch
#pragma unroll
    for (int dc = 0; dc < 4; dc++) kf[dc] = kn[dc];
  }

  // --- normalize + store ---
  const int b = bh >> 4, h = bh & 15;
  const float inv = 1.0f / l_run;
  bf16_t* orow = O + ((size_t)b * T_SEQ + q0 + l31) * C_DIM + h * DH;
#pragma unroll
  for (int db = 0; db < 2; db++) {
#pragma unroll
    for (int r = 0; r < 16; r += 2) {
      const int d = db * 32 + (r & 3) + 8 * (r >> 2) + 4 * hi;
      const float v0 = (db ? oacc1[r] : oacc0[r]) * inv;
      const float v1 = (db ? oacc1[r + 1] : oacc0[r + 1]) * inv;
      const unsigned short b0 = __builtin_bit_cast(unsigned short, (bf16_t)v0);
      const unsigned short b1 = __builtin_bit_cast(unsigned short, (bf16_t)v1);
      *reinterpret_cast<u32*>(orow + d) = ((u32)b1 << 16) | (u32)b0;
    }
  }
}

// ---------------------------------------------------------------------------
// Output projection, m97 structure (same loop as qkv, f32 epilogue)
// ---------------------------------------------------------------------------
__global__ __launch_bounds__(256) void msa_gemm_out(
    const bf16_t* __restrict__ ab, const bf16_t* __restrict__ wt,
    const float* __restrict__ bo, float* __restrict__ out) {
  __shared__ bf16_t lA[128 * 32];
  __shared__ bf16_t lB[128 * 32];
  const int tid = threadIdx.x;
  const int w = tid >> 6, lane = tid & 63;
  const int lr = lane & 15, lg = lane >> 4;
  const int m0 = blockIdx.y * 128;
  const int n0 = blockIdx.x * 128;
  const int wm = (w >> 1) * 64, wn = (w & 1) * 64;

  const int srow = tid >> 2, scol = (tid & 3) * 8;
  const bf16_t* ga = ab + (size_t)(m0 + srow) * C_DIM + scol;
  const bf16_t* gb = wt + (size_t)(n0 + srow) * C_DIM + scol;

  f32x4 acc[4][4];
#pragma unroll
  for (int i = 0; i < 4; i++)
#pragma unroll
    for (int j = 0; j < 4; j++) acc[i][j] = (f32x4){0.f, 0.f, 0.f, 0.f};

  for (int k0 = 0; k0 < C_DIM; k0 += 32) {
    gld_lds16(ga + k0, &lA[tid * 8]);
    gld_lds16(ga + (size_t)64 * C_DIM + k0, &lA[2048 + tid * 8]);
    gld_lds16(gb + k0, &lB[tid * 8]);
    gld_lds16(gb + (size_t)64 * C_DIM + k0, &lB[2048 + tid * 8]);
    __syncthreads();
    bf16x8 a[4], b[4];
#pragma unroll
    for (int mb = 0; mb < 4; mb++)
      a[mb] = *(const bf16x8*)&lA[(wm + mb * 16 + lr) * 32 + lg * 8];
#pragma unroll
    for (int nb = 0; nb < 4; nb++)
      b[nb] = *(const bf16x8*)&lB[(wn + nb * 16 + lr) * 32 + lg * 8];
#pragma unroll
    for (int mb = 0; mb < 4; mb++)
#pragma unroll
      for (int nb = 0; nb < 4; nb++)
        acc[mb][nb] = __builtin_amdgcn_mfma_f32_16x16x32_bf16(a[mb], b[nb], acc[mb][nb], 0, 0, 0);
    __syncthreads();
  }

#pragma unroll
  for (int nb = 0; nb < 4; nb++) {
    const int n = n0 + wn + nb * 16 + lr;
    const float bias = bo[n];
#pragma unroll
    for (int mb = 0; mb < 4; mb++) {
#pragma unroll
      for (int r = 0; r < 4; r++) {
        const int m = m0 + wm + mb * 16 + lg * 4 + r;
        out[(size_t)m * C_DIM + n] = acc[mb][nb][r] + bias;
      }
    }
  }
}

// ---------------------------------------------------------------------------
// launch
// ---------------------------------------------------------------------------
extern "C" void kernel_launch(void* const* d_in, const int* in_sizes, int n_in,
                              void* d_out, int out_size, void* d_ws, size_t ws_size,
                              hipStream_t stream) {
  const float* x  = (const float*)d_in[0];
  // d_in[1] = mask (causal; recomputed analytically, not read)
  const float* wq = (const float*)d_in[2];
  const float* bq = (const float*)d_in[3];
  const float* wk = (const float*)d_in[4];
  const float* bk = (const float*)d_in[5];
  const float* wv = (const float*)d_in[6];
  const float* bv = (const float*)d_in[7];
  const float* wo = (const float*)d_in[8];
  const float* bo = (const float*)d_in[9];

  char* ws = (char*)d_ws;
  bf16_t* xb     = (bf16_t*)(ws);
  bf16_t* wt_qkv = (bf16_t*)(ws + (16ull << 20));
  bf16_t* wt_o   = (bf16_t*)(ws + (22ull << 20));
  bf16_t* qb     = (bf16_t*)(ws + (24ull << 20));
  bf16_t* kb     = (bf16_t*)(ws + (40ull << 20));
  bf16_t* vtb    = (bf16_t*)(ws + (56ull << 20));
  bf16_t* attn_o = xb;  // alias: xb dead after QKV GEMM

  const int n4 = M_TOK * C_DIM / 4;
  msa_cvt_x<<<n4 / 256, 256, 0, stream>>>(x, xb, n4);
  msa_transpose_w<<<dim3(32, 32, 4), 256, 0, stream>>>(wq, wk, wv, wo, wt_qkv, wt_o);
  msa_gemm_qkv<<<dim3(24, 64), 256, 0, stream>>>(xb, wt_qkv, bq, bk, bv, qb, kb, vtb);
  msa_attn32<<<dim3(64, BATCH * NH), 64, 0, stream>>>(qb, kb, vtb, attn_o);
  msa_gemm_out<<<dim3(8, 64), 256, 0, stream>>>(attn_o, wt_o, bo, (float*)d_out);
}

// Round 4
// 229.873 us; speedup vs baseline: 3.1795x; 1.3925x over previous
//
#include <hip/hip_runtime.h>

typedef __bf16 bf16_t;
typedef bf16_t bf16x8 __attribute__((ext_vector_type(8)));
typedef bf16_t bf16x4 __attribute__((ext_vector_type(4)));
typedef float  f32x4  __attribute__((ext_vector_type(4)));
typedef float  f32x16 __attribute__((ext_vector_type(16)));
typedef unsigned int u32;
typedef u32 u32x4 __attribute__((ext_vector_type(4)));

#define T_SEQ 2048
#define C_DIM 1024
#define NH    16
#define DH    64
#define BATCH 4
#define M_TOK (BATCH * T_SEQ)   // 8192

// Q pre-scale: 1/sqrt(64) * log2(e)  -> softmax computed in exp2 domain
#define Q_SCALE 0.1803368801111137f
#define DEFER_THR 8.0f

#define AS1 __attribute__((address_space(1)))
#define AS3 __attribute__((address_space(3)))

__device__ __forceinline__ void gld_lds16(const bf16_t* g, bf16_t* l) {
  __builtin_amdgcn_global_load_lds(
      (const AS1 u32*)(uintptr_t)g,
      (AS3 u32*)(u32)(uintptr_t)l, 16, 0, 0);
}

// ---------------------------------------------------------------------------
// prep: x f32 -> bf16
// ---------------------------------------------------------------------------
__global__ __launch_bounds__(256) void msa_cvt_x(const float* __restrict__ x,
                                                 bf16_t* __restrict__ xb, int n4) {
  int i = blockIdx.x * 256 + threadIdx.x;
  if (i < n4) {
    const float4 v = ((const float4*)x)[i];
    bf16x4 o;
    o[0] = (bf16_t)v.x; o[1] = (bf16_t)v.y; o[2] = (bf16_t)v.z; o[3] = (bf16_t)v.w;
    ((bf16x4*)xb)[i] = o;
  }
}

// ---------------------------------------------------------------------------
// prep: weight transpose+convert: w[k][n] f32 -> wt[n][k] bf16
// ---------------------------------------------------------------------------
__global__ __launch_bounds__(256) void msa_transpose_w(
    const float* __restrict__ wq, const float* __restrict__ wk,
    const float* __restrict__ wv, const float* __restrict__ wo,
    bf16_t* __restrict__ wt_qkv, bf16_t* __restrict__ wt_o) {
  __shared__ float tile[32][33];
  const int a = blockIdx.z;
  const float* src = (a == 0) ? wq : (a == 1) ? wk : (a == 2) ? wv : wo;
  bf16_t* dst = (a < 3) ? (wt_qkv + (size_t)a * C_DIM * C_DIM) : wt_o;
  const int tx = threadIdx.x & 31, ty = threadIdx.x >> 5;
  const int bi = blockIdx.y * 32, bj = blockIdx.x * 32;
#pragma unroll
  for (int p = 0; p < 4; p++) {
    int r = p * 8 + ty;
    tile[r][tx] = src[(size_t)(bi + r) * C_DIM + bj + tx];
  }
  __syncthreads();
#pragma unroll
  for (int p = 0; p < 4; p++) {
    int r = p * 8 + ty;
    dst[(size_t)(bj + r) * C_DIM + bi + tx] = (bf16_t)tile[tx][r];
  }
}

// ---------------------------------------------------------------------------
// QKV GEMM, m97 structure
// ---------------------------------------------------------------------------
__global__ __launch_bounds__(256) void msa_gemm_qkv(
    const bf16_t* __restrict__ xb, const bf16_t* __restrict__ wt,
    const float* __restrict__ bq, const float* __restrict__ bk,
    const float* __restrict__ bv,
    bf16_t* __restrict__ qo, bf16_t* __restrict__ ko, bf16_t* __restrict__ vto) {
  __shared__ bf16_t lA[128 * 32];
  __shared__ bf16_t lB[128 * 32];
  const int tid = threadIdx.x;
  const int w = tid >> 6, lane = tid & 63;
  const int lr = lane & 15, lg = lane >> 4;
  const int m0 = blockIdx.y * 128;
  const int n0 = blockIdx.x * 128;
  const int wm = (w >> 1) * 64, wn = (w & 1) * 64;

  const int srow = tid >> 2, scol = (tid & 3) * 8;
  const bf16_t* ga = xb + (size_t)(m0 + srow) * C_DIM + scol;
  const bf16_t* gb = wt + (size_t)(n0 + srow) * C_DIM + scol;

  f32x4 acc[4][4];
#pragma unroll
  for (int i = 0; i < 4; i++)
#pragma unroll
    for (int j = 0; j < 4; j++) acc[i][j] = (f32x4){0.f, 0.f, 0.f, 0.f};

  for (int k0 = 0; k0 < C_DIM; k0 += 32) {
    gld_lds16(ga + k0, &lA[tid * 8]);
    gld_lds16(ga + (size_t)64 * C_DIM + k0, &lA[2048 + tid * 8]);
    gld_lds16(gb + k0, &lB[tid * 8]);
    gld_lds16(gb + (size_t)64 * C_DIM + k0, &lB[2048 + tid * 8]);
    __syncthreads();
    bf16x8 a[4], b[4];
#pragma unroll
    for (int mb = 0; mb < 4; mb++)
      a[mb] = *(const bf16x8*)&lA[(wm + mb * 16 + lr) * 32 + lg * 8];
#pragma unroll
    for (int nb = 0; nb < 4; nb++)
      b[nb] = *(const bf16x8*)&lB[(wn + nb * 16 + lr) * 32 + lg * 8];
#pragma unroll
    for (int mb = 0; mb < 4; mb++)
#pragma unroll
      for (int nb = 0; nb < 4; nb++)
        acc[mb][nb] = __builtin_amdgcn_mfma_f32_16x16x32_bf16(a[mb], b[nb], acc[mb][nb], 0, 0, 0);
    __syncthreads();
  }

#pragma unroll
  for (int nb = 0; nb < 4; nb++) {
    const int n = n0 + wn + nb * 16 + lr;
    const int g = n >> 10, c = n & 1023, h = c >> 6, d = c & 63;
    const float bias = (g == 0) ? bq[c] : (g == 1) ? bk[c] : bv[c];
#pragma unroll
    for (int mb = 0; mb < 4; mb++) {
#pragma unroll
      for (int r = 0; r < 4; r++) {
        const int m = m0 + wm + mb * 16 + lg * 4 + r;
        const int bi = m >> 11, t = m & (T_SEQ - 1);
        float v = acc[mb][nb][r] + bias;
        if (g == 0)
          qo[(((size_t)bi * NH + h) * T_SEQ + t) * DH + d] = (bf16_t)(v * Q_SCALE);
        else if (g == 1)
          ko[(((size_t)bi * NH + h) * T_SEQ + t) * DH + d] = (bf16_t)v;
        else
          vto[(((size_t)bi * NH + h) * DH + d) * T_SEQ + t] = (bf16_t)v;
      }
    }
  }
}

// ---------------------------------------------------------------------------
// attn helpers: softmax (defer-max) + pack/redistribute P to B-frag
// ---------------------------------------------------------------------------
__device__ __forceinline__ void sm_pack(f32x16& s, float& m_run, float& l_run,
                                        f32x16& o0, f32x16& o1, const int hi,
                                        bf16x8& pa0, bf16x8& pa1) {
  float m01 = fmaxf(fmaxf(s[0], s[1]), fmaxf(s[2], s[3]));
  float m23 = fmaxf(fmaxf(s[4], s[5]), fmaxf(s[6], s[7]));
  float m45 = fmaxf(fmaxf(s[8], s[9]), fmaxf(s[10], s[11]));
  float m67 = fmaxf(fmaxf(s[12], s[13]), fmaxf(s[14], s[15]));
  float mt = fmaxf(fmaxf(m01, m23), fmaxf(m45, m67));
  mt = fmaxf(mt, __shfl_xor(mt, 32));

  if (__any(mt > m_run + DEFER_THR)) {
    const float mnew = fmaxf(m_run, mt);
    const float al = __builtin_amdgcn_exp2f(m_run - mnew);
    m_run = mnew;
    l_run *= al;
#pragma unroll
    for (int r = 0; r < 16; r++) { o0[r] *= al; o1[r] *= al; }
  }

#pragma unroll
  for (int r = 0; r < 16; r++) s[r] = __builtin_amdgcn_exp2f(s[r] - m_run);
  {
    float a0 = (s[0] + s[1]) + (s[2] + s[3]);
    float a1 = (s[4] + s[5]) + (s[6] + s[7]);
    float a2 = (s[8] + s[9]) + (s[10] + s[11]);
    float a3 = (s[12] + s[13]) + (s[14] + s[15]);
    float lt = (a0 + a1) + (a2 + a3);
    lt += __shfl_xor(lt, 32);
    l_run += lt;
  }

  u32 pk8[8];
#pragma unroll
  for (int i = 0; i < 8; i++) {
    const unsigned short lo = __builtin_bit_cast(unsigned short, (bf16_t)s[2 * i]);
    const unsigned short hh = __builtin_bit_cast(unsigned short, (bf16_t)s[2 * i + 1]);
    pk8[i] = ((u32)hh << 16) | (u32)lo;
  }
  u32 xs[8];
#pragma unroll
  for (int i = 0; i < 8; i++) xs[i] = (u32)__shfl_xor((int)pk8[i], 32);

  u32x4 f0, f1;
  f0[0] = hi ? xs[2] : pk8[0];
  f0[1] = hi ? xs[3] : pk8[1];
  f0[2] = hi ? pk8[2] : xs[0];
  f0[3] = hi ? pk8[3] : xs[1];
  f1[0] = hi ? xs[6] : pk8[4];
  f1[1] = hi ? xs[7] : pk8[5];
  f1[2] = hi ? pk8[6] : xs[4];
  f1[3] = hi ? pk8[7] : xs[5];
  pa0 = __builtin_bit_cast(bf16x8, f0);
  pa1 = __builtin_bit_cast(bf16x8, f1);
}

__device__ __forceinline__ void store_o(f32x16& o0, f32x16& o1, float l_run,
                                        bf16_t* __restrict__ orow, const int hi) {
  const float inv = 1.0f / l_run;
#pragma unroll
  for (int db = 0; db < 2; db++) {
#pragma unroll
    for (int r = 0; r < 16; r += 2) {
      const int d = db * 32 + (r & 3) + 8 * (r >> 2) + 4 * hi;
      const float v0 = (db ? o1[r] : o0[r]) * inv;
      const float v1 = (db ? o1[r + 1] : o0[r + 1]) * inv;
      const unsigned short b0 = __builtin_bit_cast(unsigned short, (bf16_t)v0);
      const unsigned short b1 = __builtin_bit_cast(unsigned short, (bf16_t)v1);
      *reinterpret_cast<u32*>(orow + d) = ((u32)b1 << 16) | (u32)b0;
    }
  }
}

// ---------------------------------------------------------------------------
// Flash attention (causal): dual-stream balanced waves.
// Grid (bh=64, pair=32), 64-thread blocks. Wave handles q-tiles tL=63-p and
// tS=p of the SAME head: both streams share each K/V tile (loads halved),
// total work is 65 tile-iterations for every wave (perfect balance), and the
// two independent chains interleave for ILP while kt <= tS. linear block id
// % 8 == bh % 8 keeps each head's K/V on one XCD's L2.
// ---------------------------------------------------------------------------
__global__ __launch_bounds__(64, 2) void msa_attn32(
    const bf16_t* __restrict__ Q, const bf16_t* __restrict__ K,
    const bf16_t* __restrict__ Vt, bf16_t* __restrict__ O) {
  const int lane = threadIdx.x;
  const int l31 = lane & 31;
  const int hi = lane >> 5;
  const int bh = blockIdx.x;
  const int p = blockIdx.y;
  const int tS = p, tL = 63 - p;
  const int q0S = tS * 32, q0L = tL * 32;

  const bf16_t* Qh = Q + (size_t)bh * T_SEQ * DH;
  const bf16_t* Kh = K + (size_t)bh * T_SEQ * DH;
  const bf16_t* Vh = Vt + (size_t)bh * DH * T_SEQ;

  bf16x8 qfL[4], qfS[4];
#pragma unroll
  for (int dc = 0; dc < 4; dc++) {
    qfL[dc] = *(const bf16x8*)(Qh + (size_t)(q0L + l31) * DH + dc * 16 + hi * 8);
    qfS[dc] = *(const bf16x8*)(Qh + (size_t)(q0S + l31) * DH + dc * 16 + hi * 8);
  }

  f32x16 oL0, oL1, oS0, oS1;
#pragma unroll
  for (int r = 0; r < 16; r++) { oL0[r] = 0.f; oL1[r] = 0.f; oS0[r] = 0.f; oS1[r] = 0.f; }
  float mL = -1e30f, lL = 0.f, mS = -1e30f, lS = 0.f;

  bf16x8 kf[4];
#pragma unroll
  for (int dc = 0; dc < 4; dc++)
    kf[dc] = *(const bf16x8*)(Kh + (size_t)l31 * DH + dc * 16 + hi * 8);

  for (int kt = 0; kt <= tL; ++kt) {
    const int j0 = kt * 32;
    const int j0n = (kt < tL) ? j0 + 32 : 0;

    // prefetch next K tile + this tile's V (shared by both streams)
    bf16x8 kn[4];
#pragma unroll
    for (int dc = 0; dc < 4; dc++)
      kn[dc] = *(const bf16x8*)(Kh + (size_t)(j0n + l31) * DH + dc * 16 + hi * 8);
    bf16x8 vf00 = *(const bf16x8*)(Vh + (size_t)l31 * T_SEQ + j0 + hi * 8);
    bf16x8 vf01 = *(const bf16x8*)(Vh + (size_t)l31 * T_SEQ + j0 + 16 + hi * 8);
    bf16x8 vf10 = *(const bf16x8*)(Vh + (size_t)(32 + l31) * T_SEQ + j0 + hi * 8);
    bf16x8 vf11 = *(const bf16x8*)(Vh + (size_t)(32 + l31) * T_SEQ + j0 + 16 + hi * 8);

    const bool actS = (kt <= tS);

    // --- QK^T for both streams (independent MFMA chains) ---
    f32x16 sL, sS;
#pragma unroll
    for (int r = 0; r < 16; r++) { sL[r] = 0.f; sS[r] = 0.f; }
#pragma unroll
    for (int dc = 0; dc < 4; dc++)
      sL = __builtin_amdgcn_mfma_f32_32x32x16_bf16(kf[dc], qfL[dc], sL, 0, 0, 0);
    if (actS) {
#pragma unroll
      for (int dc = 0; dc < 4; dc++)
        sS = __builtin_amdgcn_mfma_f32_32x32x16_bf16(kf[dc], qfS[dc], sS, 0, 0, 0);
    }

    // --- causal masks (diagonal tiles only) ---
    if (kt == tL) {
#pragma unroll
      for (int r = 0; r < 16; r++) {
        const int jrow = (r & 3) + 8 * (r >> 2) + 4 * hi;
        if (jrow > l31) sL[r] = -1e30f;
      }
    }
    if (kt == tS) {
#pragma unroll
      for (int r = 0; r < 16; r++) {
        const int jrow = (r & 3) + 8 * (r >> 2) + 4 * hi;
        if (jrow > l31) sS[r] = -1e30f;
      }
    }

    // --- softmax + pack, then PV ---
    bf16x8 paL0, paL1, paS0, paS1;
    sm_pack(sL, mL, lL, oL0, oL1, hi, paL0, paL1);
    if (actS) sm_pack(sS, mS, lS, oS0, oS1, hi, paS0, paS1);

    oL0 = __builtin_amdgcn_mfma_f32_32x32x16_bf16(vf00, paL0, oL0, 0, 0, 0);
    oL1 = __builtin_amdgcn_mfma_f32_32x32x16_bf16(vf10, paL0, oL1, 0, 0, 0);
    oL0 = __builtin_amdgcn_mfma_f32_32x32x16_bf16(vf01, paL1, oL0, 0, 0, 0);
    oL1 = __builtin_amdgcn_mfma_f32_32x32x16_bf16(vf11, paL1, oL1, 0, 0, 0);
    if (actS) {
      oS0 = __builtin_amdgcn_mfma_f32_32x32x16_bf16(vf00, paS0, oS0, 0, 0, 0);
      oS1 = __builtin_amdgcn_mfma_f32_32x32x16_bf16(vf10, paS0, oS1, 0, 0, 0);
      oS0 = __builtin_amdgcn_mfma_f32_32x32x16_bf16(vf01, paS1, oS0, 0, 0, 0);
      oS1 = __builtin_amdgcn_mfma_f32_32x32x16_bf16(vf11, paS1, oS1, 0, 0, 0);
    }

#pragma unroll
    for (int dc = 0; dc < 4; dc++) kf[dc] = kn[dc];
  }

  // --- normalize + store both streams ---
  const int b = bh >> 4, h = bh & 15;
  store_o(oL0, oL1, lL, O + ((size_t)b * T_SEQ + q0L + l31) * C_DIM + h * DH, hi);
  store_o(oS0, oS1, lS, O + ((size_t)b * T_SEQ + q0S + l31) * C_DIM + h * DH, hi);
}

// ---------------------------------------------------------------------------
// Output projection, m97 structure
// ---------------------------------------------------------------------------
__global__ __launch_bounds__(256) void msa_gemm_out(
    const bf16_t* __restrict__ ab, const bf16_t* __restrict__ wt,
    const float* __restrict__ bo, float* __restrict__ out) {
  __shared__ bf16_t lA[128 * 32];
  __shared__ bf16_t lB[128 * 32];
  const int tid = threadIdx.x;
  const int w = tid >> 6, lane = tid & 63;
  const int lr = lane & 15, lg = lane >> 4;
  const int m0 = blockIdx.y * 128;
  const int n0 = blockIdx.x * 128;
  const int wm = (w >> 1) * 64, wn = (w & 1) * 64;

  const int srow = tid >> 2, scol = (tid & 3) * 8;
  const bf16_t* ga = ab + (size_t)(m0 + srow) * C_DIM + scol;
  const bf16_t* gb = wt + (size_t)(n0 + srow) * C_DIM + scol;

  f32x4 acc[4][4];
#pragma unroll
  for (int i = 0; i < 4; i++)
#pragma unroll
    for (int j = 0; j < 4; j++) acc[i][j] = (f32x4){0.f, 0.f, 0.f, 0.f};

  for (int k0 = 0; k0 < C_DIM; k0 += 32) {
    gld_lds16(ga + k0, &lA[tid * 8]);
    gld_lds16(ga + (size_t)64 * C_DIM + k0, &lA[2048 + tid * 8]);
    gld_lds16(gb + k0, &lB[tid * 8]);
    gld_lds16(gb + (size_t)64 * C_DIM + k0, &lB[2048 + tid * 8]);
    __syncthreads();
    bf16x8 a[4], b[4];
#pragma unroll
    for (int mb = 0; mb < 4; mb++)
      a[mb] = *(const bf16x8*)&lA[(wm + mb * 16 + lr) * 32 + lg * 8];
#pragma unroll
    for (int nb = 0; nb < 4; nb++)
      b[nb] = *(const bf16x8*)&lB[(wn + nb * 16 + lr) * 32 + lg * 8];
#pragma unroll
    for (int mb = 0; mb < 4; mb++)
#pragma unroll
      for (int nb = 0; nb < 4; nb++)
        acc[mb][nb] = __builtin_amdgcn_mfma_f32_16x16x32_bf16(a[mb], b[nb], acc[mb][nb], 0, 0, 0);
    __syncthreads();
  }

#pragma unroll
  for (int nb = 0; nb < 4; nb++) {
    const int n = n0 + wn + nb * 16 + lr;
    const float bias = bo[n];
#pragma unroll
    for (int mb = 0; mb < 4; mb++) {
#pragma unroll
      for (int r = 0; r < 4; r++) {
        const int m = m0 + wm + mb * 16 + lg * 4 + r;
        out[(size_t)m * C_DIM + n] = acc[mb][nb][r] + bias;
      }
    }
  }
}

// ---------------------------------------------------------------------------
// launch
// ---------------------------------------------------------------------------
extern "C" void kernel_launch(void* const* d_in, const int* in_sizes, int n_in,
                              void* d_out, int out_size, void* d_ws, size_t ws_size,
                              hipStream_t stream) {
  const float* x  = (const float*)d_in[0];
  const float* wq = (const float*)d_in[2];
  const float* bq = (const float*)d_in[3];
  const float* wk = (const float*)d_in[4];
  const float* bk = (const float*)d_in[5];
  const float* wv = (const float*)d_in[6];
  const float* bv = (const float*)d_in[7];
  const float* wo = (const float*)d_in[8];
  const float* bo = (const float*)d_in[9];

  char* ws = (char*)d_ws;
  bf16_t* xb     = (bf16_t*)(ws);
  bf16_t* wt_qkv = (bf16_t*)(ws + (16ull << 20));
  bf16_t* wt_o   = (bf16_t*)(ws + (22ull << 20));
  bf16_t* qb     = (bf16_t*)(ws + (24ull << 20));
  bf16_t* kb     = (bf16_t*)(ws + (40ull << 20));
  bf16_t* vtb    = (bf16_t*)(ws + (56ull << 20));
  bf16_t* attn_o = xb;  // alias: xb dead after QKV GEMM

  const int n4 = M_TOK * C_DIM / 4;
  msa_cvt_x<<<n4 / 256, 256, 0, stream>>>(x, xb, n4);
  msa_transpose_w<<<dim3(32, 32, 4), 256, 0, stream>>>(wq, wk, wv, wo, wt_qkv, wt_o);
  msa_gemm_qkv<<<dim3(24, 64), 256, 0, stream>>>(xb, wt_qkv, bq, bk, bv, qb, kb, vtb);
  msa_attn32<<<dim3(64, 32), 64, 0, stream>>>(qb, kb, vtb, attn_o);
  msa_gemm_out<<<dim3(8, 64), 256, 0, stream>>>(attn_o, wt_o, bo, (float*)d_out);
}